// Round 10
// baseline (2661.194 us; speedup 1.0000x reference)
//
#include <hip/hip_runtime.h>

typedef __attribute__((ext_vector_type(8)))  short          bf16x8;
typedef __attribute__((ext_vector_type(16))) float          f32x16;
typedef __attribute__((ext_vector_type(4)))  unsigned int   uint4v;
typedef __attribute__((ext_vector_type(4)))  unsigned short ushort4v;
typedef __attribute__((ext_vector_type(4)))  float          float4v;

#define DEV static __device__ __forceinline__
#define MFMA32(A,B,C) __builtin_amdgcn_mfma_f32_32x32x16_bf16(A,B,C,0,0,0)

// ---- workspace element offsets (unsigned short elements) ----
// WRES: weight tile STREAM: for st 0..6: 49x7 conv tiles + 1 last_w tile
// = 2408 tiles x 4096 shorts, frag-major [frag(ks*2+mt)][lane][8]
#define WRES_OFF 0u
#define FW_OFF   9863168u
#define P1_OFF   9913344u
#define P2_OFF   10437632u
#define ACT0_OFF 10896384u
#define PV_OFF   15090688u
#define HID_OFF  17187840u

// ---- d_out offsets (floats) ----
#define VAL_OFF 1740800
#define PID_OFF 1741824

// ---- tower LDS map: 2 images x 3 act buffers (R5 layout: pos row 128B, XOR swz) ----
#define IMG_AREA 24576          // 3 x 8192
#define SM_Z     49152          // 128B zero row
#define SM_BYTES 49280

DEV float bf2f(unsigned short u){ union { unsigned int i; float f; } v; v.i = ((unsigned int)u) << 16; return v.f; }
DEV unsigned short f2bf(float f){
  union { float f; unsigned int i; } v; v.f = f;
  unsigned int x = v.i;
  return (unsigned short)((x + 0x7fffu + ((x >> 16) & 1u)) >> 16);  // RNE
}

// ======================= weight prep (layouts unchanged) =======================
__global__ void prep_res_k(const float* __restrict__ res_w, unsigned short* __restrict__ ws){
  __shared__ float buf[3136];
  int bx = blockIdx.x;             // L*64 + o
  int L = bx >> 6, o = bx & 63;
  const float* src = res_w + (size_t)bx * 3136;
  for (int e = threadIdx.x; e < 3136; e += 256) buf[e] = src[e];
  __syncthreads();
  unsigned short* dst = ws + WRES_OFF;
  int mt = o >> 5, lrow = o & 31;
  int tilebase = L*49 + L/7;
  for (int e = threadIdx.x; e < 3136; e += 256){
    int t = e >> 6, c = e & 63;
    int ks = c >> 4, hi = (c >> 3) & 1, j = c & 7;
    int lane = hi*32 + lrow;
    dst[(size_t)(tilebase + t)*4096 + ((ks*2 + mt)*64 + lane)*8 + j] = f2bf(buf[c*49 + t]);
  }
}

__global__ void prep_misc_k(const float* __restrict__ first_w, const float* __restrict__ last_w,
                            const float* __restrict__ pfc1_w, const float* __restrict__ pfc2_w,
                            unsigned short* __restrict__ ws){
  const int n_fw = 49*1024, n_lw = 28672, n_p1 = 524288, n_p2 = 458752;
  const int total = n_fw + n_lw + n_p1 + n_p2;
  for (int d = blockIdx.x*256 + threadIdx.x; d < total; d += gridDim.x*256){
    if (d < n_fw){
      int t = d >> 10, r = d & 1023;
      int mt = r >> 9, lane = (r >> 3) & 63, j = r & 7;
      int o = mt*32 + (lane & 31);
      int c = ((lane >> 5) << 3) + j;
      float v = (o < 63 && c < 12) ? first_w[(o*12 + c)*49 + t] : 0.f;
      ws[FW_OFF + d] = f2bf(v);
    } else if (d < n_fw + n_lw){
      int e = d - n_fw;
      int st = e >> 12, r = e & 4095;
      int f = r >> 9, lane = (r >> 3) & 63, j = r & 7;
      int ks = f >> 1, mt = f & 1;
      int o = mt*32 + (lane & 31);
      int c = ks*16 + ((lane >> 5) << 3) + j;
      ws[WRES_OFF + (size_t)(st*344 + 343)*4096 + r] = f2bf(last_w[st*4096 + o*64 + c]);
    } else if (d < n_fw + n_lw + n_p1){
      int e = d - n_fw - n_lw; ws[P1_OFF + e] = f2bf(pfc1_w[e]);
    } else {
      int e = d - n_fw - n_lw - n_p1;
      int row = e >> 8, k = e & 255;
      ws[P2_OFF + e] = f2bf(row < 1700 ? pfc2_w[row*256 + k] : 0.f);
    }
  }
}

// ======================= tower =======================
#define LBAR() { asm volatile("s_waitcnt lgkmcnt(0)" ::: "memory"); \
                 __builtin_amdgcn_s_barrier(); \
                 asm volatile("" ::: "memory"); }

DEV void packst(unsigned char* sm, int scrb, int lane, int k, const f32x16& A){
  unsigned u[8];
  #pragma unroll
  for (int i = 0; i < 8; ++i)
    u[i] = (unsigned)f2bf(A[2*i]) | ((unsigned)f2bf(A[2*i+1]) << 16);
  uint4v* d = (uint4v*)(sm + scrb + k*2048 + lane*32);
  d[0] = uint4v{u[0],u[1],u[2],u[3]};
  d[1] = uint4v{u[4],u[5],u[6],u[7]};
}
DEV void ldadd(unsigned char* sm, int scrb, int lane, int k, f32x16& A){
  const uint4v* s = (const uint4v*)(sm + scrb + k*2048 + lane*32);
  uint4v a = s[0], b = s[1];
  #pragma unroll
  for (int i = 0; i < 4; ++i){
    A[2*i]     += bf2f((unsigned short)(a[i] & 0xffffu));
    A[2*i+1]   += bf2f((unsigned short)(a[i] >> 16));
    A[8+2*i]   += bf2f((unsigned short)(b[i] & 0xffffu));
    A[8+2*i+1] += bf2f((unsigned short)(b[i] >> 16));
  }
}
#define STACC(scrb) { packst(sm,(scrb),lane,0,c00); packst(sm,(scrb),lane,1,c01); \
                      packst(sm,(scrb),lane,2,c10); packst(sm,(scrb),lane,3,c11); }
#define LDADD(scrb) { ldadd(sm,(scrb),lane,0,c00); ldadd(sm,(scrb),lane,1,c01); \
                      ldadd(sm,(scrb),lane,2,c10); ldadd(sm,(scrb),lane,3,c11); }
// 4-phase serial K-reduction (kq3 -> kq2 -> kq1 -> kq0), scratch = scrb
#define REDUCE(scrb) { \
  LBAR(); if (kq == 3) STACC(scrb); \
  LBAR(); if (kq == 2){ LDADD(scrb); STACC(scrb); } \
  LBAR(); if (kq == 1){ LDADD(scrb); STACC(scrb); } \
  LBAR(); if (kq == 0){ LDADD(scrb); } }

DEV void conv_epi(const f32x16& acc, int mt, int p, int wb, int hi,
                  unsigned char* smp, const float* sp, const float* bp){
  int swz = (p & 7) << 4; int rowb = wb + (p << 7);
  #pragma unroll
  for (int rg = 0; rg < 4; ++rg){
    int o0 = mt*32 + rg*8 + hi*4;
    unsigned short bb[4];
    #pragma unroll
    for (int e = 0; e < 4; ++e){
      float v = sp[o0+e]*acc[rg*4+e] + bp[o0+e];
      v = v > 0.f ? v : 0.f;
      bb[e] = f2bf(v);
    }
    int ob = mt*64 + rg*16 + hi*8;
    *(ushort4v*)(smp + rowb + (ob ^ swz)) = ushort4v{bb[0],bb[1],bb[2],bb[3]};
  }
}

DEV void res_epi(const f32x16& acc, int mt, int p, int rsb, int wb, int hi,
                 unsigned char* smp, const float* lsp, const float* lbp){
  int swz = (p & 7) << 4;
  int rrow = rsb + (p << 7), wrow = wb + (p << 7);
  #pragma unroll
  for (int rg = 0; rg < 4; ++rg){
    int o0 = mt*32 + rg*8 + hi*4;
    int ob = mt*64 + rg*16 + hi*8;
    ushort4v rv = *(const ushort4v*)(smp + rrow + (ob ^ swz));
    unsigned short bb[4];
    #pragma unroll
    for (int e = 0; e < 4; ++e){
      float v = lsp[o0+e]*acc[rg*4+e] + lbp[o0+e] + bf2f(rv[e]);
      v = v > 0.f ? v : 0.f;
      bb[e] = f2bf(v);
    }
    *(ushort4v*)(smp + wrow + (ob ^ swz)) = ushort4v{bb[0],bb[1],bb[2],bb[3]};
  }
}

DEV void first_epi(const f32x16& acc, int mt, int p, float idsv, int img, int wb, int hi,
                   unsigned char* smp, const float* fsp, const float* fbp,
                   unsigned short* act0){
  int swz = (p & 7) << 4; int rowb = wb + (p << 7);
  #pragma unroll
  for (int rg = 0; rg < 4; ++rg){
    int o0 = mt*32 + rg*8 + hi*4;
    unsigned short bb[4];
    #pragma unroll
    for (int e = 0; e < 4; ++e){
      int o = o0 + e;
      int oc = o < 63 ? o : 62;
      float v = fsp[oc]*acc[rg*4+e] + fbp[oc];
      v = v > 0.f ? v : 0.f;
      if (o == 63) v = idsv;
      bb[e] = f2bf(v);
    }
    int ob = mt*64 + rg*16 + hi*8;
    *(ushort4v*)(smp + rowb + (ob ^ swz)) = ushort4v{bb[0],bb[1],bb[2],bb[3]};
    *(ushort4v*)(act0 + (size_t)img*4096 + p*64 + o0) = ushort4v{bb[0],bb[1],bb[2],bb[3]};
  }
}

__global__ __launch_bounds__(512, 1) void tower_k(
    const float* __restrict__ x,
    const float* __restrict__ first_s, const float* __restrict__ first_b,
    const float* __restrict__ res_s,   const float* __restrict__ res_b,
    const float* __restrict__ last_s,  const float* __restrict__ last_b,
    const float* __restrict__ vconv_w, const float* __restrict__ v_s, const float* __restrict__ v_b,
    const float* __restrict__ vfc1_w,  const float* __restrict__ vfc1_b,
    const float* __restrict__ vfc2_w,  const float* __restrict__ vfc2_b,
    const unsigned short* __restrict__ ws_r, unsigned short* __restrict__ act0,
    float* __restrict__ value_out)
{
  __shared__ unsigned char sm[SM_BYTES];
  int tid = threadIdx.x, lane = tid & 63, wave = tid >> 6;
  int imgi = wave >> 2, kq = wave & 3;      // wave = (image, K-quarter)
  int img = blockIdx.x * 2 + imgi;

  for (int i = tid*16; i < SM_BYTES; i += 512*16) *(float4v*)(sm + i) = float4v{0,0,0,0};
  __syncthreads();

  int col = lane & 31, hi = lane >> 5;
  int hi16 = hi << 4;
  int kqs  = kq << 5;                 // K-slice byte offset (XOR-composed)
  int imgbase = imgi * IMG_AREA;
  int rS = imgbase, rA = imgbase + 8192, rB = imgbase + 16384;

  int p0 = col, p1 = 32 + col;
  int py0 = p0 >> 3, px0 = p0 & 7, py1 = p1 >> 3, px1 = p1 & 7;

  // ---- stage x into padded xin (overlays rA), channels 0..11 ----
  const float* xim = x + (size_t)img * 832;
  int xinb = rA;
  if (kq == 0){
    int q = (lane >> 3)*14 + (lane & 7) + 3;
    for (int c = 0; c < 12; ++c)
      *(unsigned short*)(sm + xinb + q*32 + c*2) = f2bf(xim[c*64 + lane]);
  }
  float ids0 = xim[768 + p0];
  float ids1 = xim[768 + p1];
  __syncthreads();

  // ---- first conv (K=16): tap-split over kq (12/12/12/13 taps) ----
  {
    int t0 = kq*12, tend = (kq == 3) ? 49 : (t0 + 12);
    f32x16 c00 = {}, c01 = {}, c10 = {}, c11 = {};
    const unsigned short* fw = ws_r + FW_OFF;
    int qbx0 = py0*14 + px0, qbx1 = py1*14 + px1;
    for (int t = t0; t < tend; ++t){
      int dy = t / 7, dx = t % 7;
      bf16x8 a0 = *(const bf16x8*)(fw + t*1024 +       lane*8);
      bf16x8 a1 = *(const bf16x8*)(fw + t*1024 + 512 + lane*8);
      bool v0 = (unsigned)(py0 + dy - 3) < 8u;
      bool v1 = (unsigned)(py1 + dy - 3) < 8u;
      int q0 = qbx0 + (dy-3)*14 + dx, q1 = qbx1 + (dy-3)*14 + dx;
      bf16x8 B0 = *(const bf16x8*)(sm + (v0 ? (xinb + q0*32 + hi16) : (SM_Z + hi16)));
      bf16x8 B1 = *(const bf16x8*)(sm + (v1 ? (xinb + q1*32 + hi16) : (SM_Z + hi16)));
      c00 = MFMA32(a0, B0, c00); c10 = MFMA32(a1, B0, c10);
      c01 = MFMA32(a0, B1, c01); c11 = MFMA32(a1, B1, c11);
    }
    REDUCE(rB);
    if (kq == 0){
      first_epi(c00, 0, p0, ids0, img, rS, hi, sm, first_s, first_b, act0);
      first_epi(c10, 1, p0, ids0, img, rS, hi, sm, first_s, first_b, act0);
      first_epi(c01, 0, p1, ids1, img, rS, hi, sm, first_s, first_b, act0);
      first_epi(c11, 1, p1, ids1, img, rS, hi, sm, first_s, first_b, act0);
    }
    LBAR();
  }

  // ---- residual tower: K-split waves; A 2 frags vmem, B 2 b128 LDS, 4 MFMA/tap ----
  const unsigned short* wstream = ws_r + WRES_OFF;
  for (int st = 0; st < 7; ++st){
    int rd = rS, wr = rA;
    for (int j = 0; j < 7; ++j){
      int L = st*7 + j;
      const unsigned short* gwL = wstream + (size_t)(st*344 + j*49)*4096
                                  + kq*1024 + lane*8;   // frags (2kq, 2kq+1)
      f32x16 c00 = {}, c01 = {}, c10 = {}, c11 = {};
      #pragma unroll
      for (int t = 0; t < 49; ++t){
        const int dy = t / 7, dx = t % 7;
        bf16x8 a0 = *(const bf16x8*)(gwL + (size_t)t*4096);
        bf16x8 a1 = *(const bf16x8*)(gwL + (size_t)t*4096 + 512);
        const int off = (dy - 3)*8 + (dx - 3);
        bool v0 = ((unsigned)(py0 + dy - 3) < 8u) && ((unsigned)(px0 + dx - 3) < 8u);
        bool v1 = ((unsigned)(py1 + dy - 3) < 8u) && ((unsigned)(px1 + dx - 3) < 8u);
        int pp0 = p0 + off, pp1 = p1 + off;
        int b0 = (v0 ? (rd + (pp0 << 7) + (hi16 ^ ((pp0 & 7) << 4))) : (SM_Z + hi16)) ^ kqs;
        int b1 = (v1 ? (rd + (pp1 << 7) + (hi16 ^ ((pp1 & 7) << 4))) : (SM_Z + hi16)) ^ kqs;
        bf16x8 B0 = *(const bf16x8*)(sm + b0);
        bf16x8 B1 = *(const bf16x8*)(sm + b1);
        c00 = MFMA32(a0, B0, c00); c10 = MFMA32(a1, B0, c10);
        c01 = MFMA32(a0, B1, c01); c11 = MFMA32(a1, B1, c11);
      }
      int scr = (j == 0) ? rB : rd;
      REDUCE(scr);
      if (kq == 0){
        const float* sp = res_s + L*64;
        const float* bp = res_b + L*64;
        conv_epi(c00, 0, p0, wr, hi, sm, sp, bp);
        conv_epi(c10, 1, p0, wr, hi, sm, sp, bp);
        conv_epi(c01, 0, p1, wr, hi, sm, sp, bp);
        conv_epi(c11, 1, p1, wr, hi, sm, sp, bp);
      }
      LBAR();
      int nrd = wr; wr = (j == 0) ? rB : rd; rd = nrd;
    }
    // 1x1 (last_w) + bn + residual(from rS) + relu -> rB ; K-split + reduce
    {
      const unsigned short* wt = wstream + (size_t)(st*344 + 343)*4096 + kq*1024 + lane*8;
      bf16x8 a0 = *(const bf16x8*)(wt);
      bf16x8 a1 = *(const bf16x8*)(wt + 512);
      f32x16 c00 = {}, c01 = {}, c10 = {}, c11 = {};
      int b0 = (rd + (p0 << 7) + (hi16 ^ ((p0 & 7) << 4))) ^ kqs;
      int b1 = (rd + (p1 << 7) + (hi16 ^ ((p1 & 7) << 4))) ^ kqs;
      bf16x8 B0 = *(const bf16x8*)(sm + b0);
      bf16x8 B1 = *(const bf16x8*)(sm + b1);
      c00 = MFMA32(a0, B0, c00); c10 = MFMA32(a1, B0, c10);
      c01 = MFMA32(a0, B1, c01); c11 = MFMA32(a1, B1, c11);
      REDUCE(rd);
      if (kq == 0){
        const float* lsp = last_s + st*64;
        const float* lbp = last_b + st*64;
        res_epi(c00, 0, p0, rS, rB, hi, sm, lsp, lbp);
        res_epi(c10, 1, p0, rS, rB, hi, sm, lsp, lbp);
        res_epi(c01, 0, p1, rS, rB, hi, sm, lsp, lbp);
        res_epi(c11, 1, p1, rS, rB, hi, sm, lsp, lbp);
      }
      LBAR();
      int ns = rB; rB = rS; rS = ns;   // new stage input = 1x1 output
    }
  }

  // ---- value head: final acts in rS; kq0 wave of each image finishes it ----
  __syncthreads();
  if (kq == 0){
    float accv = 0.f;
    int rowa = rS + (lane << 7);
    int swz = (lane & 7) << 4;
    #pragma unroll
    for (int k = 0; k < 8; ++k){
      bf16x8 av = *(const bf16x8*)(sm + rowa + ((k*16) ^ swz));
      #pragma unroll
      for (int jj = 0; jj < 8; ++jj)
        accv += bf2f((unsigned short)av[jj]) * vconv_w[k*8 + jj];
    }
    float vv = v_s[0]*accv + v_b[0];
    vv = vv > 0.f ? vv : 0.f;
    float* vbuf = (float*)(sm + rA);
    vbuf[lane] = vv;
    asm volatile("s_waitcnt lgkmcnt(0)" ::: "memory");
    float hidv[4];
    #pragma unroll
    for (int it = 0; it < 4; ++it){
      int jj = it*64 + lane;
      float a = vfc1_b[jj];
      for (int k = 0; k < 64; k += 4){
        float4v v4 = *(const float4v*)(vbuf + k);
        a += vfc1_w[jj*64+k]*v4[0] + vfc1_w[jj*64+k+1]*v4[1]
           + vfc1_w[jj*64+k+2]*v4[2] + vfc1_w[jj*64+k+3]*v4[3];
      }
      hidv[it] = a > 0.f ? a : 0.f;
    }
    float tot = 0.f;
    #pragma unroll
    for (int it = 0; it < 4; ++it) tot += hidv[it]*vfc2_w[it*64 + lane];
    #pragma unroll
    for (int off = 32; off; off >>= 1) tot += __shfl_xor(tot, off);
    if (lane == 0) value_out[img] = tanhf(tot + vfc2_b[0]);
  }
}

// ======================= gather / piece head =======================
__global__ __launch_bounds__(256) void gather_k(const unsigned short* __restrict__ act0,
                                                unsigned short* __restrict__ pvec,
                                                float* __restrict__ pid_out){
  int lane = threadIdx.x & 63, wave = threadIdx.x >> 6;
  int img = blockIdx.x*4 + wave;
  const unsigned short* arow = act0 + (size_t)img*4096;
  int myid = (int)bf2f(arow[lane*64 + 63]);
  int mypos = 0, mypres = 0;
  for (int p = 0; p < 32; ++p){
    unsigned long long m = __ballot(myid == (p+1));
    if (lane == p){ mypres = (m != 0ull); mypos = mypres ? (__ffsll(m) - 1) : 0; }
  }
  if (lane < 32){
    float v = mypres ? (float)(lane+1) : 0.f;
    #pragma unroll
    for (int s = 0; s < 8; ++s) pid_out[(size_t)img*256 + s*32 + lane] = v;
  }
  for (int p = 0; p < 32; ++p){
    int q  = __shfl(mypos, p);
    int pr = __shfl(mypres, p);
    unsigned short v = pr ? arow[q*64 + lane] : (unsigned short)0;
    pvec[(size_t)img*2048 + p*64 + lane] = v;
  }
}

// ======================= policy head GEMMs =======================
__global__ __launch_bounds__(256) void fc1_k(const unsigned short* __restrict__ pvec,
                                             const unsigned short* __restrict__ w,
                                             const float* __restrict__ bias,
                                             unsigned short* __restrict__ hid){
  int lane = threadIdx.x & 63, wave = threadIdx.x >> 6;
  int col = lane & 31, hi = lane >> 5;
  int wm = wave >> 1, wn = wave & 1;
  int m0 = blockIdx.x*128 + wm*64;
  int n0 = blockIdx.y*128 + wn*64;
  f32x16 a00 = {}, a01 = {}, a10 = {}, a11 = {};
  for (int k = 0; k < 2048; k += 16){
    bf16x8 A0 = *(const bf16x8*)(pvec + (size_t)(m0+col)*2048    + k + hi*8);
    bf16x8 A1 = *(const bf16x8*)(pvec + (size_t)(m0+32+col)*2048 + k + hi*8);
    bf16x8 B0 = *(const bf16x8*)(w + (size_t)(n0+col)*2048    + k + hi*8);
    bf16x8 B1 = *(const bf16x8*)(w + (size_t)(n0+32+col)*2048 + k + hi*8);
    a00 = MFMA32(A0, B0, a00); a01 = MFMA32(A0, B1, a01);
    a10 = MFMA32(A1, B0, a10); a11 = MFMA32(A1, B1, a11);
  }
  #pragma unroll
  for (int mt = 0; mt < 2; ++mt)
    #pragma unroll
    for (int nt = 0; nt < 2; ++nt){
      const f32x16& acc = mt == 0 ? (nt == 0 ? a00 : a01) : (nt == 0 ? a10 : a11);
      int jcol = n0 + nt*32 + col;
      float bj = bias[jcol];
      #pragma unroll
      for (int rg = 0; rg < 4; ++rg)
        #pragma unroll
        for (int e = 0; e < 4; ++e){
          int n = m0 + mt*32 + rg*8 + hi*4 + e;
          float v = acc[rg*4+e] + bj; v = v > 0.f ? v : 0.f;
          hid[(size_t)n*256 + jcol] = f2bf(v);
        }
    }
}

__global__ __launch_bounds__(256) void fc2_k(const unsigned short* __restrict__ hid,
                                             const unsigned short* __restrict__ w,
                                             const float* __restrict__ bias,
                                             float* __restrict__ pol){
  int lane = threadIdx.x & 63, wave = threadIdx.x >> 6;
  int col = lane & 31, hi = lane >> 5;
  int wm = wave >> 1, wn = wave & 1;
  int m0 = blockIdx.x*128 + wm*64;
  int n0 = blockIdx.y*128 + wn*64;
  f32x16 a00 = {}, a01 = {}, a10 = {}, a11 = {};
  for (int k = 0; k < 256; k += 16){
    bf16x8 A0 = *(const bf16x8*)(hid + (size_t)(m0+col)*256    + k + hi*8);
    bf16x8 A1 = *(const bf16x8*)(hid + (size_t)(m0+32+col)*256 + k + hi*8);
    bf16x8 B0 = *(const bf16x8*)(w + (size_t)(n0+col)*256    + k + hi*8);
    bf16x8 B1 = *(const bf16x8*)(w + (size_t)(n0+32+col)*256 + k + hi*8);
    a00 = MFMA32(A0, B0, a00); a01 = MFMA32(A0, B1, a01);
    a10 = MFMA32(A1, B0, a10); a11 = MFMA32(A1, B1, a11);
  }
  #pragma unroll
  for (int mt = 0; mt < 2; ++mt)
    #pragma unroll
    for (int nt = 0; nt < 2; ++nt){
      const f32x16& acc = mt == 0 ? (nt == 0 ? a00 : a01) : (nt == 0 ? a10 : a11);
      int jcol = n0 + nt*32 + col;
      if (jcol < 1700){
        float bj = bias[jcol];
        #pragma unroll
        for (int rg = 0; rg < 4; ++rg)
          #pragma unroll
          for (int e = 0; e < 4; ++e){
            int n = m0 + mt*32 + rg*8 + hi*4 + e;
            pol[(size_t)n*1700 + jcol] = acc[rg*4+e] + bj;
          }
      }
    }
}

// ======================= launch =======================
extern "C" void kernel_launch(void* const* d_in, const int* in_sizes, int n_in,
                              void* d_out, int out_size, void* d_ws, size_t ws_size,
                              hipStream_t stream){
  const float* x       = (const float*)d_in[0];
  const float* first_w = (const float*)d_in[1];
  const float* first_s = (const float*)d_in[2];
  const float* first_b = (const float*)d_in[3];
  const float* res_w   = (const float*)d_in[4];
  const float* res_s   = (const float*)d_in[5];
  const float* res_b   = (const float*)d_in[6];
  const float* last_w  = (const float*)d_in[7];
  const float* last_s  = (const float*)d_in[8];
  const float* last_b  = (const float*)d_in[9];
  const float* pfc1_w  = (const float*)d_in[10];
  const float* pfc1_b  = (const float*)d_in[11];
  const float* pfc2_w  = (const float*)d_in[12];
  const float* pfc2_b  = (const float*)d_in[13];
  const float* vconv_w = (const float*)d_in[14];
  const float* v_s     = (const float*)d_in[15];
  const float* v_b     = (const float*)d_in[16];
  const float* vfc1_w  = (const float*)d_in[17];
  const float* vfc1_b  = (const float*)d_in[18];
  const float* vfc2_w  = (const float*)d_in[19];
  const float* vfc2_b  = (const float*)d_in[20];
  unsigned short* ws = (unsigned short*)d_ws;
  float* out = (float*)d_out;

  prep_res_k <<<3136, 256, 0, stream>>>(res_w, ws);
  prep_misc_k<<<1024, 256, 0, stream>>>(first_w, last_w, pfc1_w, pfc2_w, ws);
  tower_k    <<<512, 512, 0, stream>>>(x, first_s, first_b, res_s, res_b, last_s, last_b,
                                       vconv_w, v_s, v_b, vfc1_w, vfc1_b, vfc2_w, vfc2_b,
                                       ws, ws + ACT0_OFF, out + VAL_OFF);
  gather_k   <<<256, 256, 0, stream>>>(ws + ACT0_OFF, ws + PV_OFF, out + PID_OFF);
  fc1_k      <<<dim3(8, 2), 256, 0, stream>>>(ws + PV_OFF, ws + P1_OFF, pfc1_b, ws + HID_OFF);
  fc2_k      <<<dim3(8, 14), 256, 0, stream>>>(ws + HID_OFF, ws + P2_OFF, pfc2_b, out);
}

// Round 11
// 1555.108 us; speedup vs baseline: 1.7113x; 1.7113x over previous
//
#include <hip/hip_runtime.h>

typedef __attribute__((ext_vector_type(8)))  short          bf16x8;
typedef __attribute__((ext_vector_type(16))) float          f32x16;
typedef __attribute__((ext_vector_type(4)))  unsigned int   uint4v;
typedef __attribute__((ext_vector_type(4)))  unsigned short ushort4v;
typedef __attribute__((ext_vector_type(4)))  float          float4v;

#define DEV static __device__ __forceinline__
#define MFMA32(A,B,C) __builtin_amdgcn_mfma_f32_32x32x16_bf16(A,B,C,0,0,0)

// ---- workspace element offsets (unsigned short elements) ----
#define WRES_OFF 0u
#define FW_OFF   9863168u
#define P1_OFF   9913344u
#define P2_OFF   10437632u
#define ACT0_OFF 10896384u
#define PV_OFF   15090688u
#define HID_OFF  17187840u

// ---- d_out offsets (floats) ----
#define VAL_OFF 1740800
#define PID_OFF 1741824

// ---- tower LDS: 2 images x 3 act buffers (pos row 128B, XOR swz) + zero row ----
#define IMG_AREA 24576          // 3 x 8192
#define SM_Z     49152
#define SM_BYTES 49280

DEV float bf2f(unsigned short u){ union { unsigned int i; float f; } v; v.i = ((unsigned int)u) << 16; return v.f; }
DEV unsigned short f2bf(float f){
  union { float f; unsigned int i; } v; v.f = f;
  unsigned int x = v.i;
  return (unsigned short)((x + 0x7fffu + ((x >> 16) & 1u)) >> 16);  // RNE
}

// ======================= weight prep (layouts unchanged) =======================
__global__ void prep_res_k(const float* __restrict__ res_w, unsigned short* __restrict__ ws){
  __shared__ float buf[3136];
  int bx = blockIdx.x;             // L*64 + o
  int L = bx >> 6, o = bx & 63;
  const float* src = res_w + (size_t)bx * 3136;
  for (int e = threadIdx.x; e < 3136; e += 256) buf[e] = src[e];
  __syncthreads();
  unsigned short* dst = ws + WRES_OFF;
  int mt = o >> 5, lrow = o & 31;
  int tilebase = L*49 + L/7;
  for (int e = threadIdx.x; e < 3136; e += 256){
    int t = e >> 6, c = e & 63;
    int ks = c >> 4, hi = (c >> 3) & 1, j = c & 7;
    int lane = hi*32 + lrow;
    dst[(size_t)(tilebase + t)*4096 + ((ks*2 + mt)*64 + lane)*8 + j] = f2bf(buf[c*49 + t]);
  }
}

__global__ void prep_misc_k(const float* __restrict__ first_w, const float* __restrict__ last_w,
                            const float* __restrict__ pfc1_w, const float* __restrict__ pfc2_w,
                            unsigned short* __restrict__ ws){
  const int n_fw = 49*1024, n_lw = 28672, n_p1 = 524288, n_p2 = 458752;
  const int total = n_fw + n_lw + n_p1 + n_p2;
  for (int d = blockIdx.x*256 + threadIdx.x; d < total; d += gridDim.x*256){
    if (d < n_fw){
      int t = d >> 10, r = d & 1023;
      int mt = r >> 9, lane = (r >> 3) & 63, j = r & 7;
      int o = mt*32 + (lane & 31);
      int c = ((lane >> 5) << 3) + j;
      float v = (o < 63 && c < 12) ? first_w[(o*12 + c)*49 + t] : 0.f;
      ws[FW_OFF + d] = f2bf(v);
    } else if (d < n_fw + n_lw){
      int e = d - n_fw;
      int st = e >> 12, r = e & 4095;
      int f = r >> 9, lane = (r >> 3) & 63, j = r & 7;
      int ks = f >> 1, mt = f & 1;
      int o = mt*32 + (lane & 31);
      int c = ks*16 + ((lane >> 5) << 3) + j;
      ws[WRES_OFF + (size_t)(st*344 + 343)*4096 + r] = f2bf(last_w[st*4096 + o*64 + c]);
    } else if (d < n_fw + n_lw + n_p1){
      int e = d - n_fw - n_lw; ws[P1_OFF + e] = f2bf(pfc1_w[e]);
    } else {
      int e = d - n_fw - n_lw - n_p1;
      int row = e >> 8, k = e & 255;
      ws[P2_OFF + e] = f2bf(row < 1700 ? pfc2_w[row*256 + k] : 0.f);
    }
  }
}

// ======================= tower =======================
DEV int baddr(int q, bool valid, int base, int hi16){
  return valid ? (base + (q << 7) + (hi16 ^ ((q & 7) << 4))) : (SM_Z + hi16);
}

#define LBAR() { asm volatile("s_waitcnt lgkmcnt(0)" ::: "memory"); \
                 __builtin_amdgcn_s_barrier(); \
                 asm volatile("" ::: "memory"); }

DEV void packst(unsigned char* sm, int scrb, int lane, int k, const f32x16& A){
  unsigned u[8];
  #pragma unroll
  for (int i = 0; i < 8; ++i)
    u[i] = (unsigned)f2bf(A[2*i]) | ((unsigned)f2bf(A[2*i+1]) << 16);
  uint4v* d = (uint4v*)(sm + scrb + k*2048 + lane*32);
  d[0] = uint4v{u[0],u[1],u[2],u[3]};
  d[1] = uint4v{u[4],u[5],u[6],u[7]};
}
DEV void ldadd(unsigned char* sm, int scrb, int lane, int k, f32x16& A){
  const uint4v* s = (const uint4v*)(sm + scrb + k*2048 + lane*32);
  uint4v a = s[0], b = s[1];
  #pragma unroll
  for (int i = 0; i < 4; ++i){
    A[2*i]     += bf2f((unsigned short)(a[i] & 0xffffu));
    A[2*i+1]   += bf2f((unsigned short)(a[i] >> 16));
    A[8+2*i]   += bf2f((unsigned short)(b[i] & 0xffffu));
    A[8+2*i+1] += bf2f((unsigned short)(b[i] >> 16));
  }
}
#define STACC(scrb) { packst(sm,(scrb),lane,0,c00); packst(sm,(scrb),lane,1,c01); \
                      packst(sm,(scrb),lane,2,c10); packst(sm,(scrb),lane,3,c11); }
#define LDADD(scrb) { ldadd(sm,(scrb),lane,0,c00); ldadd(sm,(scrb),lane,1,c01); \
                      ldadd(sm,(scrb),lane,2,c10); ldadd(sm,(scrb),lane,3,c11); }
#define REDUCE(scrb) { \
  LBAR(); if (tq == 3) STACC(scrb); \
  LBAR(); if (tq == 2){ LDADD(scrb); STACC(scrb); } \
  LBAR(); if (tq == 1){ LDADD(scrb); STACC(scrb); } \
  LBAR(); if (tq == 0){ LDADD(scrb); } }

DEV void conv_epi(const f32x16& acc, int mt, int p, int wb, int hi,
                  unsigned char* smp, const float* sp, const float* bp){
  int swz = (p & 7) << 4; int rowb = wb + (p << 7);
  #pragma unroll
  for (int rg = 0; rg < 4; ++rg){
    int o0 = mt*32 + rg*8 + hi*4;
    unsigned short bb[4];
    #pragma unroll
    for (int e = 0; e < 4; ++e){
      float v = sp[o0+e]*acc[rg*4+e] + bp[o0+e];
      v = v > 0.f ? v : 0.f;
      bb[e] = f2bf(v);
    }
    int ob = mt*64 + rg*16 + hi*8;
    *(ushort4v*)(smp + rowb + (ob ^ swz)) = ushort4v{bb[0],bb[1],bb[2],bb[3]};
  }
}

DEV void res_epi(const f32x16& acc, int mt, int p, int rsb, int wb, int hi,
                 unsigned char* smp, const float* lsp, const float* lbp){
  int swz = (p & 7) << 4;
  int rrow = rsb + (p << 7), wrow = wb + (p << 7);
  #pragma unroll
  for (int rg = 0; rg < 4; ++rg){
    int o0 = mt*32 + rg*8 + hi*4;
    int ob = mt*64 + rg*16 + hi*8;
    ushort4v rv = *(const ushort4v*)(smp + rrow + (ob ^ swz));
    unsigned short bb[4];
    #pragma unroll
    for (int e = 0; e < 4; ++e){
      float v = lsp[o0+e]*acc[rg*4+e] + lbp[o0+e] + bf2f(rv[e]);
      v = v > 0.f ? v : 0.f;
      bb[e] = f2bf(v);
    }
    *(ushort4v*)(smp + wrow + (ob ^ swz)) = ushort4v{bb[0],bb[1],bb[2],bb[3]};
  }
}

DEV void first_epi(const f32x16& acc, int mt, int p, float idsv, int img, int wb, int hi,
                   unsigned char* smp, const float* fsp, const float* fbp,
                   unsigned short* act0){
  int swz = (p & 7) << 4; int rowb = wb + (p << 7);
  #pragma unroll
  for (int rg = 0; rg < 4; ++rg){
    int o0 = mt*32 + rg*8 + hi*4;
    unsigned short bb[4];
    #pragma unroll
    for (int e = 0; e < 4; ++e){
      int o = o0 + e;
      int oc = o < 63 ? o : 62;
      float v = fsp[oc]*acc[rg*4+e] + fbp[oc];
      v = v > 0.f ? v : 0.f;
      if (o == 63) v = idsv;
      bb[e] = f2bf(v);
    }
    int ob = mt*64 + rg*16 + hi*8;
    *(ushort4v*)(smp + rowb + (ob ^ swz)) = ushort4v{bb[0],bb[1],bb[2],bb[3]};
    *(ushort4v*)(act0 + (size_t)img*4096 + p*64 + o0) = ushort4v{bb[0],bb[1],bb[2],bb[3]};
  }
}

__global__ __launch_bounds__(512, 4) void tower_k(
    const float* __restrict__ x,
    const float* __restrict__ first_s, const float* __restrict__ first_b,
    const float* __restrict__ res_s,   const float* __restrict__ res_b,
    const float* __restrict__ last_s,  const float* __restrict__ last_b,
    const float* __restrict__ vconv_w, const float* __restrict__ v_s, const float* __restrict__ v_b,
    const float* __restrict__ vfc1_w,  const float* __restrict__ vfc1_b,
    const float* __restrict__ vfc2_w,  const float* __restrict__ vfc2_b,
    const unsigned short* __restrict__ ws_r, unsigned short* __restrict__ act0,
    float* __restrict__ value_out)
{
  __shared__ unsigned char sm[SM_BYTES];
  int tid = threadIdx.x, lane = tid & 63, wave = tid >> 6;
  int imgi = wave >> 2, tq = wave & 3;      // wave = (image, tap-quarter)
  int img = blockIdx.x * 2 + imgi;

  for (int i = tid*16; i < SM_BYTES; i += 512*16) *(float4v*)(sm + i) = float4v{0,0,0,0};
  __syncthreads();

  int col = lane & 31, hi = lane >> 5;
  int hi16 = hi << 4;
  int imgbase = imgi * IMG_AREA;
  int rS = imgbase, rA = imgbase + 8192, rB = imgbase + 16384;

  int p0 = col, p1 = 32 + col;
  int py0 = p0 >> 3, px0 = p0 & 7, py1 = p1 >> 3, px1 = p1 & 7;
  int t0 = tq*12, tend = (tq == 3) ? 49 : (t0 + 12);

  // ---- stage x into padded xin (overlays rA), channels 0..11 ----
  const float* xim = x + (size_t)img * 832;
  int xinb = rA;
  if (tq == 0){
    int q = (lane >> 3)*14 + (lane & 7) + 3;
    for (int c = 0; c < 12; ++c)
      *(unsigned short*)(sm + xinb + q*32 + c*2) = f2bf(xim[c*64 + lane]);
  }
  float ids0 = xim[768 + p0];
  float ids1 = xim[768 + p1];
  __syncthreads();

  // ---- first conv (K=16), tap-split; full 64x64 output per wave ----
  {
    f32x16 c00 = {}, c01 = {}, c10 = {}, c11 = {};
    const unsigned short* fw = ws_r + FW_OFF;
    int qbx0 = py0*14 + px0, qbx1 = py1*14 + px1;
    for (int t = t0; t < tend; ++t){
      int dy = t / 7, dx = t % 7;
      bf16x8 a0 = *(const bf16x8*)(fw + t*1024 +       lane*8);
      bf16x8 a1 = *(const bf16x8*)(fw + t*1024 + 512 + lane*8);
      bool v0 = (unsigned)(py0 + dy - 3) < 8u;
      bool v1 = (unsigned)(py1 + dy - 3) < 8u;
      int q0 = qbx0 + (dy-3)*14 + dx, q1 = qbx1 + (dy-3)*14 + dx;
      bf16x8 B0 = *(const bf16x8*)(sm + (v0 ? (xinb + q0*32 + hi16) : (SM_Z + hi16)));
      bf16x8 B1 = *(const bf16x8*)(sm + (v1 ? (xinb + q1*32 + hi16) : (SM_Z + hi16)));
      c00 = MFMA32(a0, B0, c00); c10 = MFMA32(a1, B0, c10);
      c01 = MFMA32(a0, B1, c01); c11 = MFMA32(a1, B1, c11);
    }
    REDUCE(rB);
    if (tq == 0){
      first_epi(c00, 0, p0, ids0, img, rS, hi, sm, first_s, first_b, act0);
      first_epi(c10, 1, p0, ids0, img, rS, hi, sm, first_s, first_b, act0);
      first_epi(c01, 0, p1, ids1, img, rS, hi, sm, first_s, first_b, act0);
      first_epi(c11, 1, p1, ids1, img, rS, hi, sm, first_s, first_b, act0);
    }
    LBAR();
  }

  // ---- residual tower: tap-split waves ----
  const unsigned short* wstream = ws_r + WRES_OFF;
  for (int st = 0; st < 7; ++st){
    int rd = rS, wr = rA;
    for (int j = 0; j < 7; ++j){
      int L = st*7 + j;
      const unsigned short* gwL = wstream + (size_t)(st*344 + j*49)*4096 + lane*8;
      f32x16 c00 = {}, c01 = {}, c10 = {}, c11 = {};
      for (int t = t0; t < tend; ++t){
        int dy = t / 7, dx = t % 7;
        int off = (dy - 3)*8 + (dx - 3);
        bool v0 = ((unsigned)(py0 + dy - 3) < 8u) && ((unsigned)(px0 + dx - 3) < 8u);
        bool v1 = ((unsigned)(py1 + dy - 3) < 8u) && ((unsigned)(px1 + dx - 3) < 8u);
        int b0 = baddr(p0 + off, v0, rd, hi16);
        int b1 = baddr(p1 + off, v1, rd, hi16);
        const unsigned short* wt = gwL + (size_t)t*4096;
        #pragma unroll
        for (int ks = 0; ks < 4; ++ks){
          bf16x8 a0 = *(const bf16x8*)(wt + (ks*2    )*512);
          bf16x8 a1 = *(const bf16x8*)(wt + (ks*2 + 1)*512);
          bf16x8 B0 = *(const bf16x8*)(sm + (b0 ^ (ks << 5)));
          bf16x8 B1 = *(const bf16x8*)(sm + (b1 ^ (ks << 5)));
          c00 = MFMA32(a0, B0, c00); c10 = MFMA32(a1, B0, c10);
          c01 = MFMA32(a0, B1, c01); c11 = MFMA32(a1, B1, c11);
        }
      }
      int scr = (j == 0) ? rB : rd;
      REDUCE(scr);
      if (tq == 0){
        const float* sp = res_s + L*64;
        const float* bp = res_b + L*64;
        conv_epi(c00, 0, p0, wr, hi, sm, sp, bp);
        conv_epi(c10, 1, p0, wr, hi, sm, sp, bp);
        conv_epi(c01, 0, p1, wr, hi, sm, sp, bp);
        conv_epi(c11, 1, p1, wr, hi, sm, sp, bp);
      }
      LBAR();
      int nrd = wr; wr = (j == 0) ? rB : rd; rd = nrd;
    }
    // 1x1 (last_w) + bn + residual(from rS) + relu -> rB ; tq0 only (full K)
    if (tq == 0){
      const unsigned short* wt = wstream + (size_t)(st*344 + 343)*4096 + lane*8;
      f32x16 c00 = {}, c01 = {}, c10 = {}, c11 = {};
      int b0 = baddr(p0, true, rd, hi16);
      int b1 = baddr(p1, true, rd, hi16);
      #pragma unroll
      for (int ks = 0; ks < 4; ++ks){
        bf16x8 a0 = *(const bf16x8*)(wt + (ks*2    )*512);
        bf16x8 a1 = *(const bf16x8*)(wt + (ks*2 + 1)*512);
        bf16x8 B0 = *(const bf16x8*)(sm + (b0 ^ (ks << 5)));
        bf16x8 B1 = *(const bf16x8*)(sm + (b1 ^ (ks << 5)));
        c00 = MFMA32(a0, B0, c00); c10 = MFMA32(a1, B0, c10);
        c01 = MFMA32(a0, B1, c01); c11 = MFMA32(a1, B1, c11);
      }
      const float* lsp = last_s + st*64;
      const float* lbp = last_b + st*64;
      res_epi(c00, 0, p0, rS, rB, hi, sm, lsp, lbp);
      res_epi(c10, 1, p0, rS, rB, hi, sm, lsp, lbp);
      res_epi(c01, 0, p1, rS, rB, hi, sm, lsp, lbp);
      res_epi(c11, 1, p1, rS, rB, hi, sm, lsp, lbp);
    }
    LBAR();
    int ns = rB; rB = rS; rS = ns;   // new stage input = 1x1 output
  }

  // ---- value head: final acts in rS; tq0 wave of each image finishes it ----
  __syncthreads();
  if (tq == 0){
    float accv = 0.f;
    int rowa = rS + (lane << 7);
    int swz = (lane & 7) << 4;
    #pragma unroll
    for (int k = 0; k < 8; ++k){
      bf16x8 av = *(const bf16x8*)(sm + rowa + ((k*16) ^ swz));
      #pragma unroll
      for (int jj = 0; jj < 8; ++jj)
        accv += bf2f((unsigned short)av[jj]) * vconv_w[k*8 + jj];
    }
    float vv = v_s[0]*accv + v_b[0];
    vv = vv > 0.f ? vv : 0.f;
    float* vbuf = (float*)(sm + rA);
    vbuf[lane] = vv;
    asm volatile("s_waitcnt lgkmcnt(0)" ::: "memory");
    float hidv[4];
    #pragma unroll
    for (int it = 0; it < 4; ++it){
      int jj = it*64 + lane;
      float a = vfc1_b[jj];
      for (int k = 0; k < 64; k += 4){
        float4v v4 = *(const float4v*)(vbuf + k);
        a += vfc1_w[jj*64+k]*v4[0] + vfc1_w[jj*64+k+1]*v4[1]
           + vfc1_w[jj*64+k+2]*v4[2] + vfc1_w[jj*64+k+3]*v4[3];
      }
      hidv[it] = a > 0.f ? a : 0.f;
    }
    float tot = 0.f;
    #pragma unroll
    for (int it = 0; it < 4; ++it) tot += hidv[it]*vfc2_w[it*64 + lane];
    #pragma unroll
    for (int off = 32; off; off >>= 1) tot += __shfl_xor(tot, off);
    if (lane == 0) value_out[img] = tanhf(tot + vfc2_b[0]);
  }
}

// ======================= gather / piece head =======================
__global__ __launch_bounds__(256) void gather_k(const unsigned short* __restrict__ act0,
                                                unsigned short* __restrict__ pvec,
                                                float* __restrict__ pid_out){
  int lane = threadIdx.x & 63, wave = threadIdx.x >> 6;
  int img = blockIdx.x*4 + wave;
  const unsigned short* arow = act0 + (size_t)img*4096;
  int myid = (int)bf2f(arow[lane*64 + 63]);
  int mypos = 0, mypres = 0;
  for (int p = 0; p < 32; ++p){
    unsigned long long m = __ballot(myid == (p+1));
    if (lane == p){ mypres = (m != 0ull); mypos = mypres ? (__ffsll(m) - 1) : 0; }
  }
  if (lane < 32){
    float v = mypres ? (float)(lane+1) : 0.f;
    #pragma unroll
    for (int s = 0; s < 8; ++s) pid_out[(size_t)img*256 + s*32 + lane] = v;
  }
  for (int p = 0; p < 32; ++p){
    int q  = __shfl(mypos, p);
    int pr = __shfl(mypres, p);
    unsigned short v = pr ? arow[q*64 + lane] : (unsigned short)0;
    pvec[(size_t)img*2048 + p*64 + lane] = v;
  }
}

// ======================= policy head GEMMs =======================
__global__ __launch_bounds__(256) void fc1_k(const unsigned short* __restrict__ pvec,
                                             const unsigned short* __restrict__ w,
                                             const float* __restrict__ bias,
                                             unsigned short* __restrict__ hid){
  int lane = threadIdx.x & 63, wave = threadIdx.x >> 6;
  int col = lane & 31, hi = lane >> 5;
  int wm = wave >> 1, wn = wave & 1;
  int m0 = blockIdx.x*128 + wm*64;
  int n0 = blockIdx.y*128 + wn*64;
  f32x16 a00 = {}, a01 = {}, a10 = {}, a11 = {};
  for (int k = 0; k < 2048; k += 16){
    bf16x8 A0 = *(const bf16x8*)(pvec + (size_t)(m0+col)*2048    + k + hi*8);
    bf16x8 A1 = *(const bf16x8*)(pvec + (size_t)(m0+32+col)*2048 + k + hi*8);
    bf16x8 B0 = *(const bf16x8*)(w + (size_t)(n0+col)*2048    + k + hi*8);
    bf16x8 B1 = *(const bf16x8*)(w + (size_t)(n0+32+col)*2048 + k + hi*8);
    a00 = MFMA32(A0, B0, a00); a01 = MFMA32(A0, B1, a01);
    a10 = MFMA32(A1, B0, a10); a11 = MFMA32(A1, B1, a11);
  }
  #pragma unroll
  for (int mt = 0; mt < 2; ++mt)
    #pragma unroll
    for (int nt = 0; nt < 2; ++nt){
      const f32x16& acc = mt == 0 ? (nt == 0 ? a00 : a01) : (nt == 0 ? a10 : a11);
      int jcol = n0 + nt*32 + col;
      float bj = bias[jcol];
      #pragma unroll
      for (int rg = 0; rg < 4; ++rg)
        #pragma unroll
        for (int e = 0; e < 4; ++e){
          int n = m0 + mt*32 + rg*8 + hi*4 + e;
          float v = acc[rg*4+e] + bj; v = v > 0.f ? v : 0.f;
          hid[(size_t)n*256 + jcol] = f2bf(v);
        }
    }
}

__global__ __launch_bounds__(256) void fc2_k(const unsigned short* __restrict__ hid,
                                             const unsigned short* __restrict__ w,
                                             const float* __restrict__ bias,
                                             float* __restrict__ pol){
  int lane = threadIdx.x & 63, wave = threadIdx.x >> 6;
  int col = lane & 31, hi = lane >> 5;
  int wm = wave >> 1, wn = wave & 1;
  int m0 = blockIdx.x*128 + wm*64;
  int n0 = blockIdx.y*128 + wn*64;
  f32x16 a00 = {}, a01 = {}, a10 = {}, a11 = {};
  for (int k = 0; k < 256; k += 16){
    bf16x8 A0 = *(const bf16x8*)(hid + (size_t)(m0+col)*256    + k + hi*8);
    bf16x8 A1 = *(const bf16x8*)(hid + (size_t)(m0+32+col)*256 + k + hi*8);
    bf16x8 B0 = *(const bf16x8*)(w + (size_t)(n0+col)*256    + k + hi*8);
    bf16x8 B1 = *(const bf16x8*)(w + (size_t)(n0+32+col)*256 + k + hi*8);
    a00 = MFMA32(A0, B0, a00); a01 = MFMA32(A0, B1, a01);
    a10 = MFMA32(A1, B0, a10); a11 = MFMA32(A1, B1, a11);
  }
  #pragma unroll
  for (int mt = 0; mt < 2; ++mt)
    #pragma unroll
    for (int nt = 0; nt < 2; ++nt){
      const f32x16& acc = mt == 0 ? (nt == 0 ? a00 : a01) : (nt == 0 ? a10 : a11);
      int jcol = n0 + nt*32 + col;
      if (jcol < 1700){
        float bj = bias[jcol];
        #pragma unroll
        for (int rg = 0; rg < 4; ++rg)
          #pragma unroll
          for (int e = 0; e < 4; ++e){
            int n = m0 + mt*32 + rg*8 + hi*4 + e;
            pol[(size_t)n*1700 + jcol] = acc[rg*4+e] + bj;
          }
      }
    }
}

// ======================= launch =======================
extern "C" void kernel_launch(void* const* d_in, const int* in_sizes, int n_in,
                              void* d_out, int out_size, void* d_ws, size_t ws_size,
                              hipStream_t stream){
  const float* x       = (const float*)d_in[0];
  const float* first_w = (const float*)d_in[1];
  const float* first_s = (const float*)d_in[2];
  const float* first_b = (const float*)d_in[3];
  const float* res_w   = (const float*)d_in[4];
  const float* res_s   = (const float*)d_in[5];
  const float* res_b   = (const float*)d_in[6];
  const float* last_w  = (const float*)d_in[7];
  const float* last_s  = (const float*)d_in[8];
  const float* last_b  = (const float*)d_in[9];
  const float* pfc1_w  = (const float*)d_in[10];
  const float* pfc1_b  = (const float*)d_in[11];
  const float* pfc2_w  = (const float*)d_in[12];
  const float* pfc2_b  = (const float*)d_in[13];
  const float* vconv_w = (const float*)d_in[14];
  const float* v_s     = (const float*)d_in[15];
  const float* v_b     = (const float*)d_in[16];
  const float* vfc1_w  = (const float*)d_in[17];
  const float* vfc1_b  = (const float*)d_in[18];
  const float* vfc2_w  = (const float*)d_in[19];
  const float* vfc2_b  = (const float*)d_in[20];
  unsigned short* ws = (unsigned short*)d_ws;
  float* out = (float*)d_out;

  prep_res_k <<<3136, 256, 0, stream>>>(res_w, ws);
  prep_misc_k<<<1024, 256, 0, stream>>>(first_w, last_w, pfc1_w, pfc2_w, ws);
  tower_k    <<<512, 512, 0, stream>>>(x, first_s, first_b, res_s, res_b, last_s, last_b,
                                       vconv_w, v_s, v_b, vfc1_w, vfc1_b, vfc2_w, vfc2_b,
                                       ws, ws + ACT0_OFF, out + VAL_OFF);
  gather_k   <<<256, 256, 0, stream>>>(ws + ACT0_OFF, ws + PV_OFF, out + PID_OFF);
  fc1_k      <<<dim3(8, 2), 256, 0, stream>>>(ws + PV_OFF, ws + P1_OFF, pfc1_b, ws + HID_OFF);
  fc2_k      <<<dim3(8, 14), 256, 0, stream>>>(ws + HID_OFF, ws + P2_OFF, pfc2_b, out);
}